// Round 7
// baseline (688.696 us; speedup 1.0000x reference)
//
#include <hip/hip_runtime.h>
#include <math.h>

// ---------------------------------------------------------------------------
// VQ-VAE forward, B=4096. Scalar f32 loss in d_out[0].
//
// ws float layout:
//   wt2g @ 0      : 18432  conv2 W   [(ci*9+tap)*64 + co]
//   Tg   @ 18432  : 33280  convT1 table [code(65)][kh*4+kw][co(32)], row64=0
//   wtd2g@ 51712  : 1536   convT2 W  [(ci*16+tap)*3 + co]
//   w1tg @ 53248  : 864    conv1 W   [(ci*9+tap)*32 + co]
//   normg@ 54112  : 64     ||emb_k||^2
//   tokens @ byte 217088   : 4096*64 uchar
// ---------------------------------------------------------------------------

__global__ __launch_bounds__(256) void k_init(
    const float* __restrict__ w1, const float* __restrict__ w2,
    const float* __restrict__ wd2, float* __restrict__ ws,
    float* __restrict__ out)
{
  int gid = blockIdx.x * 256 + threadIdx.x;
  if (gid == 0) out[0] = 0.f;
  if (gid < 18432) {                       // w2: (64co,32ci,3,3) -> [(ci*9+tap)*64+co]
    int co = gid / 288, j = gid - co*288;
    ws[j*64 + co] = w2[gid];
  }
  if (gid < 1536) {                        // wd2: (32ci,3co,4,4) -> [(ci*16+tap)*3+co]
    int ci = gid / 48, r = gid - ci*48, co = r >> 4, k = r & 15;
    ws[51712 + (ci*16 + k)*3 + co] = wd2[gid];
  }
  if (gid < 864) {                         // w1: (32co,3ci,3,3) -> [(ci*9+tap)*32+co]
    int co = gid / 27, j = gid - co*27;
    ws[53248 + j*32 + co] = w1[gid];
  }
}

// ---------------------------------------------------------------------------
// k_tab: T[code][tap][co] = sum_ci emb[code][ci] * wd1[ci][co][tap]. Row 64 = 0.
// Block 64 also writes ||emb_k||^2. grid 65 x 512.
// ---------------------------------------------------------------------------
__global__ __launch_bounds__(512) void k_tab(
    const float* __restrict__ emb, const float* __restrict__ wd1,
    float* __restrict__ ws)
{
  float* Tg = ws + 18432;
  const int code = blockIdx.x;
  const int tid = threadIdx.x;
  if (code == 64) {
    Tg[64*512 + tid] = 0.f;
    if (tid < 64) {
      const float* e = emb + tid*64;
      float s = 0.f;
      for (int j = 0; j < 64; j++) s += e[j]*e[j];
      ws[54112 + tid] = s;
    }
    return;
  }
  __shared__ float wsh[4096];
  float acc = 0.f;
  for (int cc = 0; cc < 8; cc++) {
    for (int i = tid; i < 4096; i += 512) wsh[i] = wd1[cc*4096 + i];
    __syncthreads();
    const float* eb = emb + code*64 + cc*8;
#pragma unroll
    for (int cil = 0; cil < 8; cil++) acc += eb[cil] * wsh[cil*512 + tid];
    __syncthreads();
  }
  Tg[code*512 + (tid & 15)*32 + (tid >> 4)] = acc;
}

// ---------------------------------------------------------------------------
// k_enc: FULL image per block (grid 4096). conv1 -> conv2 (wave-uniform
// SGPR weights via readfirstlane) -> in-LDS x_enc -> VQ argmin + loss.
// LDS: h1[32][17][19]=10336 @0 | xt[3][34][35]=3570 / xe[64][68]=4352 @10336
//      enat[64][68] @0 (after conv2) | norms @14688 | red @14752.
// ---------------------------------------------------------------------------
__global__ __launch_bounds__(256) void k_enc(
    const float* __restrict__ x,
    const float* __restrict__ b1v, const float* __restrict__ b2v,
    const float* __restrict__ emb,
    const float* __restrict__ ws,
    unsigned char* __restrict__ tokens,
    float* __restrict__ loss)
{
  __shared__ __align__(16) float smem[14760];
  float* h1    = smem;           // [32][17][19]
  float* enat  = smem;           // alias after conv2
  float* xt    = smem + 10336;   // [3][34][35]
  float* xe    = smem + 10336;   // [64][68] (xt dead by then)
  float* norms = smem + 14688;
  float* red   = smem + 14752;

  const int tid = threadIdx.x;
  const int b = blockIdx.x;
  const float* w1tg = ws + 53248;

  // ---- phase 0: zero h1+xt, stage x interior, norms ----
  {
    float4* s4 = (float4*)smem;
    float4 z = make_float4(0.f, 0.f, 0.f, 0.f);
    for (int i = tid; i < 3477; i += 256) s4[i] = z;   // covers 13908 >= 13906
    if (tid < 64) norms[tid] = ws[54112 + tid];
  }
  __syncthreads();
  {
    const float* xb = x + b*3072;
    for (int idx = tid; idx < 3072; idx += 256) {
      int ci = idx >> 10, rem = idx & 1023;
      int r = rem >> 5, c = rem & 31;
      xt[ci*1190 + (r + 1)*35 + (c + 1)] = xb[idx];
    }
  }
  __syncthreads();

  // ---- phase 1: conv1 (3->32, k3 s2 p1) + ReLU -> h1 bordered ----
  // wave-uniform co-group (8 co per wave-quarter group cs): SGPR weights.
  {
    const int cs = __builtin_amdgcn_readfirstlane(tid >> 6);  // 0..3
    const int l = tid & 63;
    float acc[4][8];
#pragma unroll
    for (int i = 0; i < 4; i++)
#pragma unroll
      for (int q = 0; q < 8; q++) acc[i][q] = 0.f;
#pragma unroll
    for (int ci = 0; ci < 3; ci++)
#pragma unroll
      for (int kh = 0; kh < 3; kh++)
#pragma unroll
        for (int kw = 0; kw < 3; kw++) {
          const float* wp = &w1tg[(ci*9 + kh*3 + kw)*32 + cs*8];
          float w0 = wp[0], w1_ = wp[1], w2_ = wp[2], w3 = wp[3];
          float w4 = wp[4], w5 = wp[5], w6 = wp[6], w7 = wp[7];
#pragma unroll
          for (int i = 0; i < 4; i++) {
            int sp = i*64 + l;
            int oh = sp >> 4, ow = sp & 15;
            float xv = xt[ci*1190 + (2*oh + kh)*35 + (2*ow + kw)];
            acc[i][0] += w0*xv; acc[i][1] += w1_*xv; acc[i][2] += w2_*xv; acc[i][3] += w3*xv;
            acc[i][4] += w4*xv; acc[i][5] += w5*xv; acc[i][6] += w6*xv; acc[i][7] += w7*xv;
          }
        }
#pragma unroll
    for (int q = 0; q < 8; q++) {
      float bias = b1v[cs*8 + q];
#pragma unroll
      for (int i = 0; i < 4; i++) {
        int sp = i*64 + l;
        int oh = sp >> 4, ow = sp & 15;
        float v = acc[i][q] + bias;
        h1[(cs*8 + q)*323 + (oh + 1)*19 + (ow + 1)] = v > 0.f ? v : 0.f;
      }
    }
  }
  __syncthreads();

  // ---- phase 2: conv2 (32->64, k3 s2 p1): lane=token, wave=16 co ----
  {
    const int wv = __builtin_amdgcn_readfirstlane(tid >> 6);  // 0..3
    const int l = tid & 63;
    const int h = l & 7, w = l >> 3;      // token t = w*8+h = l
    float acc[16];
#pragma unroll
    for (int q = 0; q < 16; q++) acc[q] = 0.f;
    const float* wbase = ws + wv*16;      // + ci*576 + tap*64
    const float* hb = h1 + (2*h)*19 + 2*w;
#pragma unroll 2
    for (int ci = 0; ci < 32; ci++) {
      const float* hc = hb + ci*323;
      float v00 = hc[0],  v01 = hc[1],  v02 = hc[2];
      float v10 = hc[19], v11 = hc[20], v12 = hc[21];
      float v20 = hc[38], v21 = hc[39], v22 = hc[40];
      const float* wp = wbase + ci*576;
#define TAP(VV, T) { const float* wq = wp + (T)*64; \
    _Pragma("unroll") for (int q = 0; q < 16; q++) acc[q] += wq[q]*(VV); }
      TAP(v00, 0) TAP(v01, 1) TAP(v02, 2)
      TAP(v10, 3) TAP(v11, 4) TAP(v12, 5)
      TAP(v20, 6) TAP(v21, 7) TAP(v22, 8)
#undef TAP
    }
    // write xe swizzled: bank = (5t + C) mod 32 -> only t/t+32 pair (free)
#pragma unroll
    for (int q = 0; q < 16; q++) {
      int d = wv*16 + q;
      xe[l*68 + ((d + l) & 63)] = acc[q] + b2v[d];
    }
  }
  __syncthreads();

  // ---- phase 3: stage emb natural [64][68] over h1 region ----
  for (int i = tid; i < 4096; i += 256) {
    int k = i >> 6, d = i & 63;
    enat[k*68 + d] = emb[i];
  }
  __syncthreads();

  // ---- phase 4: VQ argmin, 4 lanes per token ----
  {
    const int dq = tid & 3, t = tid >> 2;
    float xq[16];
#pragma unroll
    for (int j = 0; j < 16; j++)
      xq[j] = xe[t*68 + ((dq*16 + j + t) & 63)];
    float best = 3.4e38f; int bestk = 0;
    for (int k = 0; k < 64; k++) {
      const float4* ep = (const float4*)&enat[k*68 + dq*16];
      float dot = 0.f;
#pragma unroll
      for (int u = 0; u < 4; u++) {
        float4 e = ep[u];
        dot += e.x*xq[u*4+0] + e.y*xq[u*4+1] + e.z*xq[u*4+2] + e.w*xq[u*4+3];
      }
      dot += __shfl_xor(dot, 1);
      dot += __shfl_xor(dot, 2);
      float sc = norms[k] - 2.f*dot;
      if (sc < best) { best = sc; bestk = k; }
    }
    const float4* ep = (const float4*)&enat[bestk*68 + dq*16];
    float dd = 0.f;
#pragma unroll
    for (int u = 0; u < 4; u++) {
      float4 e = ep[u];
      float t0 = e.x - xq[u*4+0], t1 = e.y - xq[u*4+1];
      float t2 = e.z - xq[u*4+2], t3 = e.w - xq[u*4+3];
      dd += t0*t0 + t1*t1 + t2*t2 + t3*t3;
    }
    dd += __shfl_xor(dd, 1);
    dd += __shfl_xor(dd, 2);
    float val = 0.f;
    if (dq == 0) {
      tokens[b*64 + t] = (unsigned char)bestk;
      val = sqrtf(fmaxf(dd, 0.f));
    }
#pragma unroll
    for (int off = 1; off < 64; off <<= 1) val += __shfl_xor(val, off);
    if ((tid & 63) == 0) red[tid >> 6] = val;
    __syncthreads();
    if (tid == 0) atomicAdd(loss, (red[0]+red[1]+red[2]+red[3]) * (1.1f/4096.f));
  }
}

// ---------------------------------------------------------------------------
// k45: per image: table-gather convT1 (+bias+ReLU, bf16 dl) -> convT2 fused
// with recon loss. grid 4096 x 256.
// ---------------------------------------------------------------------------
__global__ __launch_bounds__(256) void k45(
    const float* __restrict__ x,
    const float* __restrict__ bd1v, const float* __restrict__ bd2v,
    const float* __restrict__ ws,
    const unsigned char* __restrict__ tokens,
    float* __restrict__ loss)
{
  __shared__ __align__(16) float smem[7400];
  unsigned short* dlu = (unsigned short*)smem;   // dl bf16 [32][18][20]
  float* wtd2s = smem + 5760;
  int*   tok_s = (int*)(smem + 7296);
  float* red   = smem + 7360;
  float* bd1s  = smem + 7368;

  const int tid = threadIdx.x;
  const int b = blockIdx.x;
  const float4* Tg4 = (const float4*)(ws + 18432);
  const float* wtd2g = ws + 51712;

  {
    float4* s4 = (float4*)smem;
    float4 z = make_float4(0.f, 0.f, 0.f, 0.f);
    for (int i = tid; i < 1440; i += 256) s4[i] = z;
    for (int i = tid; i < 1536; i += 256) wtd2s[i] = wtd2g[i];
    if (tid < 64) tok_s[tid] = tokens[b*64 + tid];
    if (tid < 32) bd1s[tid] = bd1v[tid];
  }
  __syncthreads();

  {
    const int oh = tid >> 4, ow = tid & 15;
    const int i0 = oh >> 1, r = oh & 1;
    const int jc = ow >> 1, c = ow & 1;
    const int kh0 = r ? 2 : 1, ih0 = i0;
    const int kh1 = r ? 0 : 3, ih1 = r ? i0 + 1 : i0 - 1;
    const int kw0 = c ? 2 : 1, iw0 = jc;
    const int kw1 = c ? 0 : 3, iw1 = c ? jc + 1 : jc - 1;
    const int c00 = tok_s[iw0*8 + ih0];
    const int c01 = ((unsigned)iw1 < 8u) ? tok_s[iw1*8 + ih0] : 64;
    const int c10 = ((unsigned)ih1 < 8u) ? tok_s[iw0*8 + ih1] : 64;
    const int c11 = (((unsigned)ih1 < 8u) && ((unsigned)iw1 < 8u)) ? tok_s[iw1*8 + ih1] : 64;
    const int b00 = (c00*16 + kh0*4 + kw0)*8;
    const int b01 = (c01*16 + kh0*4 + kw1)*8;
    const int b10 = (c10*16 + kh1*4 + kw0)*8;
    const int b11 = (c11*16 + kh1*4 + kw1)*8;
    unsigned short* dw = dlu + (oh + 1)*20 + (ow + 1);
#pragma unroll
    for (int u = 0; u < 8; u++) {
      float4 t0 = Tg4[b00 + u], t1 = Tg4[b01 + u], t2 = Tg4[b10 + u], t3 = Tg4[b11 + u];
      float4 s;
      s.x = (t0.x + t1.x) + (t2.x + t3.x);
      s.y = (t0.y + t1.y) + (t2.y + t3.y);
      s.z = (t0.z + t1.z) + (t2.z + t3.z);
      s.w = (t0.w + t1.w) + (t2.w + t3.w);
      int co = u*4;
      float v0 = s.x + bd1s[co+0]; v0 = v0 > 0.f ? v0 : 0.f;
      float v1 = s.y + bd1s[co+1]; v1 = v1 > 0.f ? v1 : 0.f;
      float v2 = s.z + bd1s[co+2]; v2 = v2 > 0.f ? v2 : 0.f;
      float v3 = s.w + bd1s[co+3]; v3 = v3 > 0.f ? v3 : 0.f;
      dw[(co+0)*360] = (unsigned short)((__float_as_uint(v0) + 0x8000u) >> 16);
      dw[(co+1)*360] = (unsigned short)((__float_as_uint(v1) + 0x8000u) >> 16);
      dw[(co+2)*360] = (unsigned short)((__float_as_uint(v2) + 0x8000u) >> 16);
      dw[(co+3)*360] = (unsigned short)((__float_as_uint(v3) + 0x8000u) >> 16);
    }
  }
  __syncthreads();

  {
    const int oh = tid >> 3;
    const int ow0 = (tid & 7) * 4;
    const int p_h = (oh + 1) & 1;
    const int ihh = (oh + 1) >> 1;
    const int iwb = ow0 >> 1;
    const unsigned* dl32 = (const unsigned*)dlu;
    const float4* wf = (const float4*)wtd2s;
    float acc[3][4];
#pragma unroll
    for (int co = 0; co < 3; co++)
#pragma unroll
      for (int u = 0; u < 4; u++) acc[co][u] = 0.f;

    for (int ci = 0; ci < 32; ci++) {
      float v[2][4];
#pragma unroll
      for (int dh = 0; dh < 2; dh++) {
        int row = ihh - dh + 1;
        int us0 = ci*360 + row*20 + iwb;
        unsigned ua = dl32[us0 >> 1];
        unsigned ub = dl32[(us0 >> 1) + 1];
        v[dh][0] = __uint_as_float(ua << 16);
        v[dh][1] = __uint_as_float(ua & 0xffff0000u);
        v[dh][2] = __uint_as_float(ub << 16);
        v[dh][3] = __uint_as_float(ub & 0xffff0000u);
      }
      float wv[2][12];
      int g0 = ci*12 + p_h*3;
      *(float4*)&wv[0][0] = wf[g0];     *(float4*)&wv[0][4] = wf[g0+1]; *(float4*)&wv[0][8] = wf[g0+2];
      *(float4*)&wv[1][0] = wf[g0+6];   *(float4*)&wv[1][4] = wf[g0+7]; *(float4*)&wv[1][8] = wf[g0+8];
#pragma unroll
      for (int u = 0; u < 4; u++) {
        const int pu = (u+1) & 1;
        const int cb_ = ((u+1) >> 1) + 1;
#pragma unroll
        for (int dh = 0; dh < 2; dh++)
#pragma unroll
          for (int dw_ = 0; dw_ < 2; dw_++) {
            float vv = v[dh][cb_ - dw_];
            acc[0][u] += vv * wv[dh][(pu + 2*dw_)*3 + 0];
            acc[1][u] += vv * wv[dh][(pu + 2*dw_)*3 + 1];
            acc[2][u] += vv * wv[dh][(pu + 2*dw_)*3 + 2];
          }
      }
    }
    float lsum = 0.f;
#pragma unroll
    for (int co = 0; co < 3; co++) {
      float4 xv = *(const float4*)&x[b*3072 + co*1024 + oh*32 + ow0];
      float bias = bd2v[co];
      float e0 = xv.x - (acc[co][0]+bias);
      float e1 = xv.y - (acc[co][1]+bias);
      float e2 = xv.z - (acc[co][2]+bias);
      float e3 = xv.w - (acc[co][3]+bias);
      lsum += e0*e0 + e1*e1 + e2*e2 + e3*e3;
    }
#pragma unroll
    for (int off = 1; off < 64; off <<= 1) lsum += __shfl_xor(lsum, off);
    if ((tid & 63) == 0) red[tid >> 6] = lsum;
    __syncthreads();
    if (tid == 0) atomicAdd(loss, (red[0]+red[1]+red[2]+red[3]) * (0.5f/4096.f));
  }
}

extern "C" void kernel_launch(void* const* d_in, const int* in_sizes, int n_in,
                              void* d_out, int out_size, void* d_ws, size_t ws_size,
                              hipStream_t stream) {
  const float* x   = (const float*)d_in[0];
  const float* w1  = (const float*)d_in[1];
  const float* b1  = (const float*)d_in[2];
  const float* w2  = (const float*)d_in[3];
  const float* b2  = (const float*)d_in[4];
  const float* wd1 = (const float*)d_in[5];
  const float* bd1 = (const float*)d_in[6];
  const float* wd2 = (const float*)d_in[7];
  const float* bd2 = (const float*)d_in[8];
  const float* emb = (const float*)d_in[9];
  float* out = (float*)d_out;
  float* ws  = (float*)d_ws;
  unsigned char* tokens = (unsigned char*)d_ws + 217088;

  k_init<<<72, 256, 0, stream>>>(w1, w2, wd2, ws, out);
  k_tab<<<65, 512, 0, stream>>>(emb, wd1, ws);
  k_enc<<<4096, 256, 0, stream>>>(x, b1, b2, emb, ws, tokens, out);
  k45<<<4096, 256, 0, stream>>>(x, bd1, bd2, ws, tokens, out);
}

// Round 8
// 502.577 us; speedup vs baseline: 1.3703x; 1.3703x over previous
//
#include <hip/hip_runtime.h>
#include <math.h>

// ---------------------------------------------------------------------------
// VQ-VAE forward, B=4096. Scalar f32 loss in d_out[0].
//
// ws float layout:
//   wt2g @ 0      : 18432  conv2 W   [(ci*9+tap)*64 + co]
//   Tg   @ 18432  : 33280  convT1 table [code(65)][kh*4+kw][co(32)], row64=0
//   wtd2g@ 51712  : 1536   convT2 W  [(ci*16+tap)*3 + co]
//   w1tg @ 53248  : 864    conv1 W   [(ci*9+tap)*32 + co]
//   normg@ 54112  : 64     ||emb_k||^2
//   tokens @ byte 217088   : 4096*64 uchar
// ---------------------------------------------------------------------------

__global__ __launch_bounds__(256) void k_init(
    const float* __restrict__ w1, const float* __restrict__ w2,
    const float* __restrict__ wd2, float* __restrict__ ws,
    float* __restrict__ out)
{
  int gid = blockIdx.x * 256 + threadIdx.x;
  if (gid == 0) out[0] = 0.f;
  if (gid < 18432) {                       // w2: (64co,32ci,3,3) -> [(ci*9+tap)*64+co]
    int co = gid / 288, j = gid - co*288;
    ws[j*64 + co] = w2[gid];
  }
  if (gid < 1536) {                        // wd2: (32ci,3co,4,4) -> [(ci*16+tap)*3+co]
    int ci = gid / 48, r = gid - ci*48, co = r >> 4, k = r & 15;
    ws[51712 + (ci*16 + k)*3 + co] = wd2[gid];
  }
  if (gid < 864) {                         // w1: (32co,3ci,3,3) -> [(ci*9+tap)*32+co]
    int co = gid / 27, j = gid - co*27;
    ws[53248 + j*32 + co] = w1[gid];
  }
}

// ---------------------------------------------------------------------------
// k_tab: T[code][tap][co] = sum_ci emb[code][ci] * wd1[ci][co][tap]. Row 64 = 0.
// Block 64 also writes ||emb_k||^2. grid 65 x 512.
// ---------------------------------------------------------------------------
__global__ __launch_bounds__(512) void k_tab(
    const float* __restrict__ emb, const float* __restrict__ wd1,
    float* __restrict__ ws)
{
  float* Tg = ws + 18432;
  const int code = blockIdx.x;
  const int tid = threadIdx.x;
  if (code == 64) {
    Tg[64*512 + tid] = 0.f;
    if (tid < 64) {
      const float* e = emb + tid*64;
      float s = 0.f;
      for (int j = 0; j < 64; j++) s += e[j]*e[j];
      ws[54112 + tid] = s;
    }
    return;
  }
  __shared__ float wsh[4096];
  float acc = 0.f;
  for (int cc = 0; cc < 8; cc++) {
    for (int i = tid; i < 4096; i += 512) wsh[i] = wd1[cc*4096 + i];
    __syncthreads();
    const float* eb = emb + code*64 + cc*8;
#pragma unroll
    for (int cil = 0; cil < 8; cil++) acc += eb[cil] * wsh[cil*512 + tid];
    __syncthreads();
  }
  Tg[code*512 + (tid & 15)*32 + (tid >> 4)] = acc;
}

// ---------------------------------------------------------------------------
// k_enc: FULL image per block (grid 4096). conv1 -> bf16 h1 -> conv2
// (wave-uniform weights) -> in-LDS x_enc -> VQ argmin + loss.
// LDS 39.5KB -> 4 blocks/CU:
//   h1b  ushort[32][17][20] = 5440 f  @ f0
//   xt   f32 [3][34][35]=3570 / xe [64][68]=4352  @ f5440
//   enat f32 [64][68] @ f0 (over h1b after conv2)
//   norms @ f9792 | red @ f9856
// ---------------------------------------------------------------------------
__global__ __launch_bounds__(256) void k_enc(
    const float* __restrict__ x,
    const float* __restrict__ b1v, const float* __restrict__ b2v,
    const float* __restrict__ emb,
    const float* __restrict__ ws,
    unsigned char* __restrict__ tokens,
    float* __restrict__ loss)
{
  __shared__ __align__(16) float smem[9864];
  unsigned short* h1b = (unsigned short*)smem;  // [32][17][20]
  float* enat  = smem;            // alias after conv2
  float* xt    = smem + 5440;     // [3][34][35]
  float* xe    = smem + 5440;     // [64][68]
  float* norms = smem + 9792;
  float* red   = smem + 9856;

  const int tid = threadIdx.x;
  const int b = blockIdx.x;
  const float* w1tg = ws + 53248;

  // ---- phase 0: zero h1b+xt, stage x interior, norms ----
  {
    float4* s4 = (float4*)smem;
    float4 z = make_float4(0.f, 0.f, 0.f, 0.f);
    for (int i = tid; i < 2253; i += 256) s4[i] = z;   // floats 0..9011 >= 9010
    if (tid < 64) norms[tid] = ws[54112 + tid];
  }
  __syncthreads();
  {
    const float* xb = x + b*3072;
    for (int idx = tid; idx < 3072; idx += 256) {
      int ci = idx >> 10, rem = idx & 1023;
      int r = rem >> 5, c = rem & 31;
      xt[ci*1190 + (r + 1)*35 + (c + 1)] = xb[idx];
    }
  }
  __syncthreads();

  // ---- phase 1: conv1 (3->32, k3 s2 p1) + ReLU -> h1b (bf16) ----
  {
    const int cs = __builtin_amdgcn_readfirstlane(tid >> 6);  // 0..3
    const int l = tid & 63;
    float acc[4][8];
#pragma unroll
    for (int i = 0; i < 4; i++)
#pragma unroll
      for (int q = 0; q < 8; q++) acc[i][q] = 0.f;
#pragma unroll
    for (int ci = 0; ci < 3; ci++)
#pragma unroll
      for (int kh = 0; kh < 3; kh++)
#pragma unroll
        for (int kw = 0; kw < 3; kw++) {
          const float* wp = &w1tg[(ci*9 + kh*3 + kw)*32 + cs*8];
          float w0 = wp[0], w1_ = wp[1], w2_ = wp[2], w3 = wp[3];
          float w4 = wp[4], w5 = wp[5], w6 = wp[6], w7 = wp[7];
#pragma unroll
          for (int i = 0; i < 4; i++) {
            int sp = i*64 + l;
            int oh = sp >> 4, ow = sp & 15;
            float xv = xt[ci*1190 + (2*oh + kh)*35 + (2*ow + kw)];
            acc[i][0] += w0*xv; acc[i][1] += w1_*xv; acc[i][2] += w2_*xv; acc[i][3] += w3*xv;
            acc[i][4] += w4*xv; acc[i][5] += w5*xv; acc[i][6] += w6*xv; acc[i][7] += w7*xv;
          }
        }
#pragma unroll
    for (int q = 0; q < 8; q++) {
      float bias = b1v[cs*8 + q];
#pragma unroll
      for (int i = 0; i < 4; i++) {
        int sp = i*64 + l;
        int oh = sp >> 4, ow = sp & 15;
        float v = acc[i][q] + bias;
        v = v > 0.f ? v : 0.f;
        h1b[(cs*8 + q)*340 + (oh + 1)*20 + (ow + 1)] =
            (unsigned short)((__float_as_uint(v) + 0x8000u) >> 16);
      }
    }
  }
  __syncthreads();

  // ---- phase 2: conv2 (32->64): lane=token, wave=16 co, uniform weights ----
  {
    const int wv = __builtin_amdgcn_readfirstlane(tid >> 6);  // 0..3
    const int l = tid & 63;
    const int h = l & 7, w = l >> 3;      // token t = w*8+h = l
    float acc[16];
#pragma unroll
    for (int q = 0; q < 16; q++) acc[q] = 0.f;
    const float* wbase = ws + wv*16;      // + ci*576 + tap*64
    const unsigned short* hb = h1b + (2*h)*20 + 2*w;
#pragma unroll 2
    for (int ci = 0; ci < 32; ci++) {
      const unsigned short* hc = hb + ci*340;
      unsigned p0 = *(const unsigned*)(hc);
      unsigned p1 = *(const unsigned*)(hc + 20);
      unsigned p2 = *(const unsigned*)(hc + 40);
      float v00 = __uint_as_float(p0 << 16), v01 = __uint_as_float(p0 & 0xffff0000u);
      float v10 = __uint_as_float(p1 << 16), v11 = __uint_as_float(p1 & 0xffff0000u);
      float v20 = __uint_as_float(p2 << 16), v21 = __uint_as_float(p2 & 0xffff0000u);
      float v02 = __uint_as_float(((unsigned)hc[2])  << 16);
      float v12 = __uint_as_float(((unsigned)hc[22]) << 16);
      float v22 = __uint_as_float(((unsigned)hc[42]) << 16);
      const float* wp = wbase + ci*576;
#define TAP(VV, T) { const float* wq = wp + (T)*64; \
    _Pragma("unroll") for (int q = 0; q < 16; q++) acc[q] += wq[q]*(VV); }
      TAP(v00, 0) TAP(v01, 1) TAP(v02, 2)
      TAP(v10, 3) TAP(v11, 4) TAP(v12, 5)
      TAP(v20, 6) TAP(v21, 7) TAP(v22, 8)
#undef TAP
    }
#pragma unroll
    for (int q = 0; q < 16; q++) {
      int d = wv*16 + q;
      xe[l*68 + ((d + l) & 63)] = acc[q] + b2v[d];
    }
  }
  __syncthreads();

  // ---- phase 3: stage emb natural [64][68] over h1b region ----
  for (int i = tid; i < 4096; i += 256) {
    int k = i >> 6, d = i & 63;
    enat[k*68 + d] = emb[i];
  }
  __syncthreads();

  // ---- phase 4: VQ argmin, 4 lanes per token ----
  {
    const int dq = tid & 3, t = tid >> 2;
    float xq[16];
#pragma unroll
    for (int j = 0; j < 16; j++)
      xq[j] = xe[t*68 + ((dq*16 + j + t) & 63)];
    float best = 3.4e38f; int bestk = 0;
    for (int k = 0; k < 64; k++) {
      const float4* ep = (const float4*)&enat[k*68 + dq*16];
      float dot = 0.f;
#pragma unroll
      for (int u = 0; u < 4; u++) {
        float4 e = ep[u];
        dot += e.x*xq[u*4+0] + e.y*xq[u*4+1] + e.z*xq[u*4+2] + e.w*xq[u*4+3];
      }
      dot += __shfl_xor(dot, 1);
      dot += __shfl_xor(dot, 2);
      float sc = norms[k] - 2.f*dot;
      if (sc < best) { best = sc; bestk = k; }
    }
    const float4* ep = (const float4*)&enat[bestk*68 + dq*16];
    float dd = 0.f;
#pragma unroll
    for (int u = 0; u < 4; u++) {
      float4 e = ep[u];
      float t0 = e.x - xq[u*4+0], t1 = e.y - xq[u*4+1];
      float t2 = e.z - xq[u*4+2], t3 = e.w - xq[u*4+3];
      dd += t0*t0 + t1*t1 + t2*t2 + t3*t3;
    }
    dd += __shfl_xor(dd, 1);
    dd += __shfl_xor(dd, 2);
    float val = 0.f;
    if (dq == 0) {
      tokens[b*64 + t] = (unsigned char)bestk;
      val = sqrtf(fmaxf(dd, 0.f));
    }
#pragma unroll
    for (int off = 1; off < 64; off <<= 1) val += __shfl_xor(val, off);
    if ((tid & 63) == 0) red[tid >> 6] = val;
    __syncthreads();
    if (tid == 0) atomicAdd(loss, (red[0]+red[1]+red[2]+red[3]) * (1.1f/4096.f));
  }
}

// ---------------------------------------------------------------------------
// k45: per image: table-gather convT1 (+bias+ReLU, bf16 dl) -> convT2 fused
// with recon loss. grid 4096 x 256.
// ---------------------------------------------------------------------------
__global__ __launch_bounds__(256) void k45(
    const float* __restrict__ x,
    const float* __restrict__ bd1v, const float* __restrict__ bd2v,
    const float* __restrict__ ws,
    const unsigned char* __restrict__ tokens,
    float* __restrict__ loss)
{
  __shared__ __align__(16) float smem[7400];
  unsigned short* dlu = (unsigned short*)smem;   // dl bf16 [32][18][20]
  float* wtd2s = smem + 5760;
  int*   tok_s = (int*)(smem + 7296);
  float* red   = smem + 7360;
  float* bd1s  = smem + 7368;

  const int tid = threadIdx.x;
  const int b = blockIdx.x;
  const float4* Tg4 = (const float4*)(ws + 18432);
  const float* wtd2g = ws + 51712;

  {
    float4* s4 = (float4*)smem;
    float4 z = make_float4(0.f, 0.f, 0.f, 0.f);
    for (int i = tid; i < 1440; i += 256) s4[i] = z;
    for (int i = tid; i < 1536; i += 256) wtd2s[i] = wtd2g[i];
    if (tid < 64) tok_s[tid] = tokens[b*64 + tid];
    if (tid < 32) bd1s[tid] = bd1v[tid];
  }
  __syncthreads();

  {
    const int oh = tid >> 4, ow = tid & 15;
    const int i0 = oh >> 1, r = oh & 1;
    const int jc = ow >> 1, c = ow & 1;
    const int kh0 = r ? 2 : 1, ih0 = i0;
    const int kh1 = r ? 0 : 3, ih1 = r ? i0 + 1 : i0 - 1;
    const int kw0 = c ? 2 : 1, iw0 = jc;
    const int kw1 = c ? 0 : 3, iw1 = c ? jc + 1 : jc - 1;
    const int c00 = tok_s[iw0*8 + ih0];
    const int c01 = ((unsigned)iw1 < 8u) ? tok_s[iw1*8 + ih0] : 64;
    const int c10 = ((unsigned)ih1 < 8u) ? tok_s[iw0*8 + ih1] : 64;
    const int c11 = (((unsigned)ih1 < 8u) && ((unsigned)iw1 < 8u)) ? tok_s[iw1*8 + ih1] : 64;
    const int b00 = (c00*16 + kh0*4 + kw0)*8;
    const int b01 = (c01*16 + kh0*4 + kw1)*8;
    const int b10 = (c10*16 + kh1*4 + kw0)*8;
    const int b11 = (c11*16 + kh1*4 + kw1)*8;
    unsigned short* dw = dlu + (oh + 1)*20 + (ow + 1);
#pragma unroll
    for (int u = 0; u < 8; u++) {
      float4 t0 = Tg4[b00 + u], t1 = Tg4[b01 + u], t2 = Tg4[b10 + u], t3 = Tg4[b11 + u];
      float4 s;
      s.x = (t0.x + t1.x) + (t2.x + t3.x);
      s.y = (t0.y + t1.y) + (t2.y + t3.y);
      s.z = (t0.z + t1.z) + (t2.z + t3.z);
      s.w = (t0.w + t1.w) + (t2.w + t3.w);
      int co = u*4;
      float v0 = s.x + bd1s[co+0]; v0 = v0 > 0.f ? v0 : 0.f;
      float v1 = s.y + bd1s[co+1]; v1 = v1 > 0.f ? v1 : 0.f;
      float v2 = s.z + bd1s[co+2]; v2 = v2 > 0.f ? v2 : 0.f;
      float v3 = s.w + bd1s[co+3]; v3 = v3 > 0.f ? v3 : 0.f;
      dw[(co+0)*360] = (unsigned short)((__float_as_uint(v0) + 0x8000u) >> 16);
      dw[(co+1)*360] = (unsigned short)((__float_as_uint(v1) + 0x8000u) >> 16);
      dw[(co+2)*360] = (unsigned short)((__float_as_uint(v2) + 0x8000u) >> 16);
      dw[(co+3)*360] = (unsigned short)((__float_as_uint(v3) + 0x8000u) >> 16);
    }
  }
  __syncthreads();

  {
    const int oh = tid >> 3;
    const int ow0 = (tid & 7) * 4;
    const int p_h = (oh + 1) & 1;
    const int ihh = (oh + 1) >> 1;
    const int iwb = ow0 >> 1;
    const unsigned* dl32 = (const unsigned*)dlu;
    const float4* wf = (const float4*)wtd2s;
    float acc[3][4];
#pragma unroll
    for (int co = 0; co < 3; co++)
#pragma unroll
      for (int u = 0; u < 4; u++) acc[co][u] = 0.f;

    for (int ci = 0; ci < 32; ci++) {
      float v[2][4];
#pragma unroll
      for (int dh = 0; dh < 2; dh++) {
        int row = ihh - dh + 1;
        int us0 = ci*360 + row*20 + iwb;
        unsigned ua = dl32[us0 >> 1];
        unsigned ub = dl32[(us0 >> 1) + 1];
        v[dh][0] = __uint_as_float(ua << 16);
        v[dh][1] = __uint_as_float(ua & 0xffff0000u);
        v[dh][2] = __uint_as_float(ub << 16);
        v[dh][3] = __uint_as_float(ub & 0xffff0000u);
      }
      float wv[2][12];
      int g0 = ci*12 + p_h*3;
      *(float4*)&wv[0][0] = wf[g0];     *(float4*)&wv[0][4] = wf[g0+1]; *(float4*)&wv[0][8] = wf[g0+2];
      *(float4*)&wv[1][0] = wf[g0+6];   *(float4*)&wv[1][4] = wf[g0+7]; *(float4*)&wv[1][8] = wf[g0+8];
#pragma unroll
      for (int u = 0; u < 4; u++) {
        const int pu = (u+1) & 1;
        const int cb_ = ((u+1) >> 1) + 1;
#pragma unroll
        for (int dh = 0; dh < 2; dh++)
#pragma unroll
          for (int dw_ = 0; dw_ < 2; dw_++) {
            float vv = v[dh][cb_ - dw_];
            acc[0][u] += vv * wv[dh][(pu + 2*dw_)*3 + 0];
            acc[1][u] += vv * wv[dh][(pu + 2*dw_)*3 + 1];
            acc[2][u] += vv * wv[dh][(pu + 2*dw_)*3 + 2];
          }
      }
    }
    float lsum = 0.f;
#pragma unroll
    for (int co = 0; co < 3; co++) {
      float4 xv = *(const float4*)&x[b*3072 + co*1024 + oh*32 + ow0];
      float bias = bd2v[co];
      float e0 = xv.x - (acc[co][0]+bias);
      float e1 = xv.y - (acc[co][1]+bias);
      float e2 = xv.z - (acc[co][2]+bias);
      float e3 = xv.w - (acc[co][3]+bias);
      lsum += e0*e0 + e1*e1 + e2*e2 + e3*e3;
    }
#pragma unroll
    for (int off = 1; off < 64; off <<= 1) lsum += __shfl_xor(lsum, off);
    if ((tid & 63) == 0) red[tid >> 6] = lsum;
    __syncthreads();
    if (tid == 0) atomicAdd(loss, (red[0]+red[1]+red[2]+red[3]) * (0.5f/4096.f));
  }
}

extern "C" void kernel_launch(void* const* d_in, const int* in_sizes, int n_in,
                              void* d_out, int out_size, void* d_ws, size_t ws_size,
                              hipStream_t stream) {
  const float* x   = (const float*)d_in[0];
  const float* w1  = (const float*)d_in[1];
  const float* b1  = (const float*)d_in[2];
  const float* w2  = (const float*)d_in[3];
  const float* b2  = (const float*)d_in[4];
  const float* wd1 = (const float*)d_in[5];
  const float* bd1 = (const float*)d_in[6];
  const float* wd2 = (const float*)d_in[7];
  const float* bd2 = (const float*)d_in[8];
  const float* emb = (const float*)d_in[9];
  float* out = (float*)d_out;
  float* ws  = (float*)d_ws;
  unsigned char* tokens = (unsigned char*)d_ws + 217088;

  k_init<<<72, 256, 0, stream>>>(w1, w2, wd2, ws, out);
  k_tab<<<65, 512, 0, stream>>>(emb, wd1, ws);
  k_enc<<<4096, 256, 0, stream>>>(x, b1, b2, emb, ws, tokens, out);
  k45<<<4096, 256, 0, stream>>>(x, bd1, bd2, ws, tokens, out);
}

// Round 9
// 333.740 us; speedup vs baseline: 2.0636x; 1.5059x over previous
//
#include <hip/hip_runtime.h>
#include <math.h>

typedef __attribute__((ext_vector_type(8))) short bf16x8;
typedef __attribute__((ext_vector_type(4))) float f32x4;

static __device__ __forceinline__ unsigned short f2bf(float v) {
  return (unsigned short)((__float_as_uint(v) + 0x8000u) >> 16);
}

// ---------------------------------------------------------------------------
// ws layout:
//   w2b (bf16) @ byte 0 : [tap(9)][co(64)][ci(32)] = 18432 ush (36864 B)
//   Tg   @ float 18432  : 33280  convT1 table [code(65)][tap][co(32)], row64=0
//   wtd2g@ float 51712  : 1536   convT2 W  [(ci*16+tap)*3 + co]
//   w1tg @ float 53248  : 864    conv1 W   [(ci*9+tap)*32 + co]
//   normg@ float 54112  : 64     ||emb_k||^2
//   tokens @ byte 217088: 4096*64 uchar
// ---------------------------------------------------------------------------

// k_initab: blocks 0..63 = convT1 table rows; 64 = zero row + norms;
// 65 = weight repacks (w2 bf16, wd2, w1) + out init. grid 66 x 512.
__global__ __launch_bounds__(512) void k_initab(
    const float* __restrict__ emb, const float* __restrict__ wd1,
    const float* __restrict__ w1, const float* __restrict__ w2,
    const float* __restrict__ wd2, float* __restrict__ ws,
    float* __restrict__ out)
{
  float* Tg = ws + 18432;
  const int code = blockIdx.x;
  const int tid = threadIdx.x;
  if (code == 65) {
    unsigned short* w2b = (unsigned short*)ws;
    for (int gid = tid; gid < 18432; gid += 512) {
      int co = gid / 288, r = gid - co*288;
      int ci = r / 9, tap = r - ci*9;
      w2b[(tap*64 + co)*32 + ci] = f2bf(w2[gid]);
    }
    for (int gid = tid; gid < 1536; gid += 512) {
      int ci = gid / 48, r = gid - ci*48, co = r >> 4, k = r & 15;
      ws[51712 + (ci*16 + k)*3 + co] = wd2[gid];
    }
    for (int gid = tid; gid < 864; gid += 512) {
      int co = gid / 27, j = gid - co*27;
      ws[53248 + j*32 + co] = w1[gid];
    }
    if (tid == 0) out[0] = 0.f;
    return;
  }
  if (code == 64) {
    Tg[64*512 + tid] = 0.f;
    if (tid < 64) {
      const float* e = emb + tid*64;
      float s = 0.f;
      for (int j = 0; j < 64; j++) s += e[j]*e[j];
      ws[54112 + tid] = s;
    }
    return;
  }
  __shared__ float wsh[4096];
  float acc = 0.f;
  for (int cc = 0; cc < 8; cc++) {
    for (int i = tid; i < 4096; i += 512) wsh[i] = wd1[cc*4096 + i];
    __syncthreads();
    const float* eb = emb + code*64 + cc*8;
#pragma unroll
    for (int cil = 0; cil < 8; cil++) acc += eb[cil] * wsh[cil*512 + tid];
    __syncthreads();
  }
  Tg[code*512 + (tid & 15)*32 + (tid >> 4)] = acc;
}

// ---------------------------------------------------------------------------
// k_enc: FULL image per block (grid 4096). conv1 -> bf16 h1 [17][17][32ci]
// -> conv2 via MFMA 16x16x32 bf16 (9 taps x 4 co-tiles) -> xe -> VQ f32.
// LDS ~36.2KB -> 4 blocks/CU:
//   h1b ush[17*17*32]=9248 (4624 f) @ f0 | enat f32[64][68] @ f0 (alias)
//   xt f32[3][34][35]=3570 @ f4624   | xe f32[64][68]=4352 @ f4624 (alias)
//   norms @ f8976 | red @ f9040
// ---------------------------------------------------------------------------
__global__ __launch_bounds__(256) void k_enc(
    const float* __restrict__ x,
    const float* __restrict__ b1v, const float* __restrict__ b2v,
    const float* __restrict__ emb,
    const float* __restrict__ ws,
    unsigned char* __restrict__ tokens,
    float* __restrict__ loss)
{
  __shared__ __align__(16) float smem[9044];
  unsigned short* h1b = (unsigned short*)smem;  // [17][17][32]
  float* enat  = smem;            // alias after conv2
  float* xt    = smem + 4624;     // [3][34][35]
  float* xe    = smem + 4624;     // [64][68]
  float* norms = smem + 8976;
  float* red   = smem + 9040;

  const int tid = threadIdx.x;
  const int b = blockIdx.x;
  const float* w1tg = ws + 53248;

  // ---- phase 0: zero h1b+xt, norms ----
  {
    float4* s4 = (float4*)smem;
    float4 z = make_float4(0.f, 0.f, 0.f, 0.f);
    for (int i = tid; i < 2049; i += 256) s4[i] = z;   // floats 0..8195
    if (tid < 64) norms[tid] = ws[54112 + tid];
  }
  __syncthreads();
  {
    const float* xb = x + b*3072;
    for (int idx = tid; idx < 3072; idx += 256) {
      int ci = idx >> 10, rem = idx & 1023;
      int r = rem >> 5, c = rem & 31;
      xt[ci*1190 + (r + 1)*35 + (c + 1)] = xb[idx];
    }
  }
  __syncthreads();

  // ---- phase 1: conv1 (3->32, k3 s2 p1) + ReLU -> h1b bf16 [r][c][ci] ----
  {
    const int cs = __builtin_amdgcn_readfirstlane(tid >> 6);  // 0..3
    const int l = tid & 63;
    float acc[4][8];
#pragma unroll
    for (int i = 0; i < 4; i++)
#pragma unroll
      for (int q = 0; q < 8; q++) acc[i][q] = 0.f;
#pragma unroll
    for (int ci = 0; ci < 3; ci++)
#pragma unroll
      for (int kh = 0; kh < 3; kh++)
#pragma unroll
        for (int kw = 0; kw < 3; kw++) {
          const float* wp = &w1tg[(ci*9 + kh*3 + kw)*32 + cs*8];
          float w0 = wp[0], w1_ = wp[1], w2_ = wp[2], w3 = wp[3];
          float w4 = wp[4], w5 = wp[5], w6 = wp[6], w7 = wp[7];
#pragma unroll
          for (int i = 0; i < 4; i++) {
            int sp = i*64 + l;
            int oh = sp >> 4, ow = sp & 15;
            float xv = xt[ci*1190 + (2*oh + kh)*35 + (2*ow + kw)];
            acc[i][0] += w0*xv; acc[i][1] += w1_*xv; acc[i][2] += w2_*xv; acc[i][3] += w3*xv;
            acc[i][4] += w4*xv; acc[i][5] += w5*xv; acc[i][6] += w6*xv; acc[i][7] += w7*xv;
          }
        }
    float bias[8];
#pragma unroll
    for (int q = 0; q < 8; q++) bias[q] = b1v[cs*8 + q];
#pragma unroll
    for (int i = 0; i < 4; i++) {
      int sp = i*64 + l;
      int oh = sp >> 4, ow = sp & 15;
      float v0 = acc[i][0] + bias[0]; v0 = v0 > 0.f ? v0 : 0.f;
      float v1 = acc[i][1] + bias[1]; v1 = v1 > 0.f ? v1 : 0.f;
      float v2 = acc[i][2] + bias[2]; v2 = v2 > 0.f ? v2 : 0.f;
      float v3 = acc[i][3] + bias[3]; v3 = v3 > 0.f ? v3 : 0.f;
      float v4 = acc[i][4] + bias[4]; v4 = v4 > 0.f ? v4 : 0.f;
      float v5 = acc[i][5] + bias[5]; v5 = v5 > 0.f ? v5 : 0.f;
      float v6 = acc[i][6] + bias[6]; v6 = v6 > 0.f ? v6 : 0.f;
      float v7 = acc[i][7] + bias[7]; v7 = v7 > 0.f ? v7 : 0.f;
      unsigned u0 = (unsigned)f2bf(v0) | ((unsigned)f2bf(v1) << 16);
      unsigned u1 = (unsigned)f2bf(v2) | ((unsigned)f2bf(v3) << 16);
      unsigned u2 = (unsigned)f2bf(v4) | ((unsigned)f2bf(v5) << 16);
      unsigned u3 = (unsigned)f2bf(v6) | ((unsigned)f2bf(v7) << 16);
      *(uint4*)&h1b[((oh + 1)*17 + (ow + 1))*32 + cs*8] = make_uint4(u0, u1, u2, u3);
    }
  }
  __syncthreads();

  // ---- phase 2: conv2 via MFMA: D[64 tok][64 co], 9 taps x 16x16x32 ----
  {
    const int tr = tid >> 6;         // wave = token tile (rows tr*16..+15)
    const int l = tid & 63;
    const int r_ = l & 15;           // A row (token) / B col (co)
    const int g = l >> 4;            // k-group (ci block of 8)
    const int t = tr*16 + r_;
    const int h = t & 7, w = t >> 3;
    const unsigned short* w2b = (const unsigned short*)ws;
    f32x4 acc0 = {0.f,0.f,0.f,0.f}, acc1 = {0.f,0.f,0.f,0.f};
    f32x4 acc2 = {0.f,0.f,0.f,0.f}, acc3 = {0.f,0.f,0.f,0.f};
#pragma unroll
    for (int kh = 0; kh < 3; kh++)
#pragma unroll
      for (int kw = 0; kw < 3; kw++) {
        const int tap = kh*3 + kw;
        bf16x8 a = *(const bf16x8*)&h1b[((2*h + kh)*17 + (2*w + kw))*32 + g*8];
        const unsigned short* bb = w2b + (tap*64 + r_)*32 + g*8;
        bf16x8 b0 = *(const bf16x8*)(bb);
        bf16x8 b1 = *(const bf16x8*)(bb + 512);
        bf16x8 b2 = *(const bf16x8*)(bb + 1024);
        bf16x8 b3 = *(const bf16x8*)(bb + 1536);
        acc0 = __builtin_amdgcn_mfma_f32_16x16x32_bf16(a, b0, acc0, 0, 0, 0);
        acc1 = __builtin_amdgcn_mfma_f32_16x16x32_bf16(a, b1, acc1, 0, 0, 0);
        acc2 = __builtin_amdgcn_mfma_f32_16x16x32_bf16(a, b2, acc2, 0, 0, 0);
        acc3 = __builtin_amdgcn_mfma_f32_16x16x32_bf16(a, b3, acc3, 0, 0, 0);
      }
    __syncthreads();   // h1b dead; xe region (over xt) about to be written
    // D layout: col(co)=lane&15, row(tok)=(lane>>4)*4+reg  [m89-verified]
#pragma unroll
    for (int rr = 0; rr < 4; rr++) {
      int t2 = tr*16 + g*4 + rr;
      xe[t2*68 + ((r_      + t2) & 63)] = acc0[rr] + b2v[r_];
      xe[t2*68 + ((r_ + 16 + t2) & 63)] = acc1[rr] + b2v[r_ + 16];
      xe[t2*68 + ((r_ + 32 + t2) & 63)] = acc2[rr] + b2v[r_ + 32];
      xe[t2*68 + ((r_ + 48 + t2) & 63)] = acc3[rr] + b2v[r_ + 48];
    }
  }
  __syncthreads();

  // ---- phase 3: stage emb natural [64][68] over h1b region ----
  for (int i = tid; i < 4096; i += 256) {
    int k = i >> 6, d = i & 63;
    enat[k*68 + d] = emb[i];
  }
  __syncthreads();

  // ---- phase 4: VQ argmin (f32, token-exact), 4 lanes per token ----
  {
    const int dq = tid & 3, t = tid >> 2;
    float xq[16];
#pragma unroll
    for (int j = 0; j < 16; j++)
      xq[j] = xe[t*68 + ((dq*16 + j + t) & 63)];
    float best = 3.4e38f; int bestk = 0;
    for (int k = 0; k < 64; k++) {
      const float4* ep = (const float4*)&enat[k*68 + dq*16];
      float dot = 0.f;
#pragma unroll
      for (int u = 0; u < 4; u++) {
        float4 e = ep[u];
        dot += e.x*xq[u*4+0] + e.y*xq[u*4+1] + e.z*xq[u*4+2] + e.w*xq[u*4+3];
      }
      dot += __shfl_xor(dot, 1);
      dot += __shfl_xor(dot, 2);
      float sc = norms[k] - 2.f*dot;
      if (sc < best) { best = sc; bestk = k; }
    }
    const float4* ep = (const float4*)&enat[bestk*68 + dq*16];
    float dd = 0.f;
#pragma unroll
    for (int u = 0; u < 4; u++) {
      float4 e = ep[u];
      float t0 = e.x - xq[u*4+0], t1 = e.y - xq[u*4+1];
      float t2 = e.z - xq[u*4+2], t3 = e.w - xq[u*4+3];
      dd += t0*t0 + t1*t1 + t2*t2 + t3*t3;
    }
    dd += __shfl_xor(dd, 1);
    dd += __shfl_xor(dd, 2);
    float val = 0.f;
    if (dq == 0) {
      tokens[b*64 + t] = (unsigned char)bestk;
      val = sqrtf(fmaxf(dd, 0.f));
    }
#pragma unroll
    for (int off = 1; off < 64; off <<= 1) val += __shfl_xor(val, off);
    if ((tid & 63) == 0) red[tid >> 6] = val;
    __syncthreads();
    if (tid == 0) atomicAdd(loss, (red[0]+red[1]+red[2]+red[3]) * (1.1f/4096.f));
  }
}

// ---------------------------------------------------------------------------
// k45: per image: table-gather convT1 (+bias+ReLU, bf16 dl) -> convT2 fused
// with recon loss. grid 4096 x 256.
// ---------------------------------------------------------------------------
__global__ __launch_bounds__(256) void k45(
    const float* __restrict__ x,
    const float* __restrict__ bd1v, const float* __restrict__ bd2v,
    const float* __restrict__ ws,
    const unsigned char* __restrict__ tokens,
    float* __restrict__ loss)
{
  __shared__ __align__(16) float smem[7400];
  unsigned short* dlu = (unsigned short*)smem;   // dl bf16 [32][18][20]
  float* wtd2s = smem + 5760;
  int*   tok_s = (int*)(smem + 7296);
  float* red   = smem + 7360;
  float* bd1s  = smem + 7368;

  const int tid = threadIdx.x;
  const int b = blockIdx.x;
  const float4* Tg4 = (const float4*)(ws + 18432);
  const float* wtd2g = ws + 51712;

  {
    float4* s4 = (float4*)smem;
    float4 z = make_float4(0.f, 0.f, 0.f, 0.f);
    for (int i = tid; i < 1440; i += 256) s4[i] = z;
    for (int i = tid; i < 1536; i += 256) wtd2s[i] = wtd2g[i];
    if (tid < 64) tok_s[tid] = tokens[b*64 + tid];
    if (tid < 32) bd1s[tid] = bd1v[tid];
  }
  __syncthreads();

  {
    const int oh = tid >> 4, ow = tid & 15;
    const int i0 = oh >> 1, r = oh & 1;
    const int jc = ow >> 1, c = ow & 1;
    const int kh0 = r ? 2 : 1, ih0 = i0;
    const int kh1 = r ? 0 : 3, ih1 = r ? i0 + 1 : i0 - 1;
    const int kw0 = c ? 2 : 1, iw0 = jc;
    const int kw1 = c ? 0 : 3, iw1 = c ? jc + 1 : jc - 1;
    const int c00 = tok_s[iw0*8 + ih0];
    const int c01 = ((unsigned)iw1 < 8u) ? tok_s[iw1*8 + ih0] : 64;
    const int c10 = ((unsigned)ih1 < 8u) ? tok_s[iw0*8 + ih1] : 64;
    const int c11 = (((unsigned)ih1 < 8u) && ((unsigned)iw1 < 8u)) ? tok_s[iw1*8 + ih1] : 64;
    const int b00 = (c00*16 + kh0*4 + kw0)*8;
    const int b01 = (c01*16 + kh0*4 + kw1)*8;
    const int b10 = (c10*16 + kh1*4 + kw0)*8;
    const int b11 = (c11*16 + kh1*4 + kw1)*8;
    unsigned short* dw = dlu + (oh + 1)*20 + (ow + 1);
#pragma unroll
    for (int u = 0; u < 8; u++) {
      float4 t0 = Tg4[b00 + u], t1 = Tg4[b01 + u], t2 = Tg4[b10 + u], t3 = Tg4[b11 + u];
      float4 s;
      s.x = (t0.x + t1.x) + (t2.x + t3.x);
      s.y = (t0.y + t1.y) + (t2.y + t3.y);
      s.z = (t0.z + t1.z) + (t2.z + t3.z);
      s.w = (t0.w + t1.w) + (t2.w + t3.w);
      int co = u*4;
      float v0 = s.x + bd1s[co+0]; v0 = v0 > 0.f ? v0 : 0.f;
      float v1 = s.y + bd1s[co+1]; v1 = v1 > 0.f ? v1 : 0.f;
      float v2 = s.z + bd1s[co+2]; v2 = v2 > 0.f ? v2 : 0.f;
      float v3 = s.w + bd1s[co+3]; v3 = v3 > 0.f ? v3 : 0.f;
      dw[(co+0)*360] = f2bf(v0);
      dw[(co+1)*360] = f2bf(v1);
      dw[(co+2)*360] = f2bf(v2);
      dw[(co+3)*360] = f2bf(v3);
    }
  }
  __syncthreads();

  {
    const int oh = tid >> 3;
    const int ow0 = (tid & 7) * 4;
    const int p_h = (oh + 1) & 1;
    const int ihh = (oh + 1) >> 1;
    const int iwb = ow0 >> 1;
    const unsigned* dl32 = (const unsigned*)dlu;
    const float4* wf = (const float4*)wtd2s;
    float acc[3][4];
#pragma unroll
    for (int co = 0; co < 3; co++)
#pragma unroll
      for (int u = 0; u < 4; u++) acc[co][u] = 0.f;

    for (int ci = 0; ci < 32; ci++) {
      float v[2][4];
#pragma unroll
      for (int dh = 0; dh < 2; dh++) {
        int row = ihh - dh + 1;
        int us0 = ci*360 + row*20 + iwb;
        unsigned ua = dl32[us0 >> 1];
        unsigned ub = dl32[(us0 >> 1) + 1];
        v[dh][0] = __uint_as_float(ua << 16);
        v[dh][1] = __uint_as_float(ua & 0xffff0000u);
        v[dh][2] = __uint_as_float(ub << 16);
        v[dh][3] = __uint_as_float(ub & 0xffff0000u);
      }
      float wv[2][12];
      int g0 = ci*12 + p_h*3;
      *(float4*)&wv[0][0] = wf[g0];     *(float4*)&wv[0][4] = wf[g0+1]; *(float4*)&wv[0][8] = wf[g0+2];
      *(float4*)&wv[1][0] = wf[g0+6];   *(float4*)&wv[1][4] = wf[g0+7]; *(float4*)&wv[1][8] = wf[g0+8];
#pragma unroll
      for (int u = 0; u < 4; u++) {
        const int pu = (u+1) & 1;
        const int cb_ = ((u+1) >> 1) + 1;
#pragma unroll
        for (int dh = 0; dh < 2; dh++)
#pragma unroll
          for (int dw_ = 0; dw_ < 2; dw_++) {
            float vv = v[dh][cb_ - dw_];
            acc[0][u] += vv * wv[dh][(pu + 2*dw_)*3 + 0];
            acc[1][u] += vv * wv[dh][(pu + 2*dw_)*3 + 1];
            acc[2][u] += vv * wv[dh][(pu + 2*dw_)*3 + 2];
          }
      }
    }
    float lsum = 0.f;
#pragma unroll
    for (int co = 0; co < 3; co++) {
      float4 xv = *(const float4*)&x[b*3072 + co*1024 + oh*32 + ow0];
      float bias = bd2v[co];
      float e0 = xv.x - (acc[co][0]+bias);
      float e1 = xv.y - (acc[co][1]+bias);
      float e2 = xv.z - (acc[co][2]+bias);
      float e3 = xv.w - (acc[co][3]+bias);
      lsum += e0*e0 + e1*e1 + e2*e2 + e3*e3;
    }
#pragma unroll
    for (int off = 1; off < 64; off <<= 1) lsum += __shfl_xor(lsum, off);
    if ((tid & 63) == 0) red[tid >> 6] = lsum;
    __syncthreads();
    if (tid == 0) atomicAdd(loss, (red[0]+red[1]+red[2]+red[3]) * (0.5f/4096.f));
  }
}

extern "C" void kernel_launch(void* const* d_in, const int* in_sizes, int n_in,
                              void* d_out, int out_size, void* d_ws, size_t ws_size,
                              hipStream_t stream) {
  const float* x   = (const float*)d_in[0];
  const float* w1  = (const float*)d_in[1];
  const float* b1  = (const float*)d_in[2];
  const float* w2  = (const float*)d_in[3];
  const float* b2  = (const float*)d_in[4];
  const float* wd1 = (const float*)d_in[5];
  const float* bd1 = (const float*)d_in[6];
  const float* wd2 = (const float*)d_in[7];
  const float* bd2 = (const float*)d_in[8];
  const float* emb = (const float*)d_in[9];
  float* out = (float*)d_out;
  float* ws  = (float*)d_ws;
  unsigned char* tokens = (unsigned char*)d_ws + 217088;

  k_initab<<<66, 512, 0, stream>>>(emb, wd1, w1, w2, wd2, ws, out);
  k_enc<<<4096, 256, 0, stream>>>(x, b1, b2, emb, ws, tokens, out);
  k45<<<4096, 256, 0, stream>>>(x, bd1, bd2, ws, tokens, out);
}